// Round 15
// baseline (198.056 us; speedup 1.0000x reference)
//
#include <hip/hip_runtime.h>
#include <cstdint>
#include <cstddef>

#define DM 2048
#define TT 2048
#define BB 2
#define HQ 16
#define HKV 4
#define HD 128

typedef _Float16 f16;
using f16x8 = __attribute__((ext_vector_type(8))) f16;
using f32x4 = __attribute__((ext_vector_type(4))) float;
using f32x16 = __attribute__((ext_vector_type(16))) float;
using u32x4 = __attribute__((ext_vector_type(4))) uint32_t;

#define MFMA16(a, b, c) __builtin_amdgcn_mfma_f32_16x16x32_f16(a, b, c, 0, 0, 0)
#define MFMA32(a, b, c) __builtin_amdgcn_mfma_f32_32x32x16_f16(a, b, c, 0, 0, 0)

typedef __attribute__((address_space(1))) const void gvoid_t;
typedef __attribute__((address_space(3))) void lvoid_t;
static __device__ __forceinline__ void gload16(const void* g, void* l) {
  __builtin_amdgcn_global_load_lds((gvoid_t*)g, (lvoid_t*)l, 16, 0, 0);
}

template <int N>
static __device__ __forceinline__ void waitvm() {
  if constexpr (N == 0) asm volatile("s_waitcnt vmcnt(0)" ::: "memory");
  else if constexpr (N == 2) asm volatile("s_waitcnt vmcnt(2)" ::: "memory");
  else if constexpr (N == 4) asm volatile("s_waitcnt vmcnt(4)" ::: "memory");
  else if constexpr (N == 5) asm volatile("s_waitcnt vmcnt(5)" ::: "memory");
  else if constexpr (N == 6) asm volatile("s_waitcnt vmcnt(6)" ::: "memory");
}

static __device__ __forceinline__ float fast_exp2(float x) {
#if __has_builtin(__builtin_amdgcn_exp2f)
  return __builtin_amdgcn_exp2f(x);
#else
  return exp2f(x);
#endif
}

static __device__ __forceinline__ uint32_t cvt_pk_u32(float a, float b) {
  auto h2 = __builtin_amdgcn_cvt_pkrtz(a, b);
  return __builtin_bit_cast(uint32_t, h2);
}

// ---- prep: fp32->f16 convert of hidden  +  all weight transposes, one launch ----
__global__ __launch_bounds__(256) void k_prep(const float* __restrict__ hidden,
                                              const float* __restrict__ Wq,
                                              const float* __restrict__ Wk,
                                              const float* __restrict__ Wv,
                                              const float* __restrict__ Wo,
                                              f16* __restrict__ Xb,
                                              f16* __restrict__ WqkvT,
                                              f16* __restrict__ WoT) {
  int t = blockIdx.x;
  int tid = threadIdx.x;
  if (t < 4096) {  // convert: 8 floats per thread
    int i = t * 256 + tid;
    const float4* pin = (const float4*)hidden;
    float4 a = pin[2 * i], b = pin[2 * i + 1];
    f16x8 o = {(f16)a.x, (f16)a.y, (f16)a.z, (f16)a.w,
               (f16)b.x, (f16)b.y, (f16)b.z, (f16)b.w};
    *(f16x8*)&Xb[(size_t)8 * i] = o;
    return;
  }
  __shared__ float tile[32][33];
  t -= 4096;
  const float* in;
  f16* out;
  int N, nx;
  if (t < 4096) {
    in = Wq; out = WqkvT; N = 2048; nx = 64;
  } else if (t < 5120) {
    t -= 4096; in = Wk; out = WqkvT + (size_t)2048 * 2048; N = 512; nx = 16;
  } else if (t < 6144) {
    t -= 5120; in = Wv; out = WqkvT + (size_t)2560 * 2048; N = 512; nx = 16;
  } else {
    t -= 6144; in = Wo; out = WoT; N = 2048; nx = 64;
  }
  int n0 = (t % nx) * 32, k0 = (t / nx) * 32;
  int tx = tid & 31, ty = tid >> 5;
#pragma unroll
  for (int r = 0; r < 32; r += 8) tile[ty + r][tx] = in[(size_t)(k0 + ty + r) * N + n0 + tx];
  __syncthreads();
#pragma unroll
  for (int r = 0; r < 32; r += 8)
    out[(size_t)(n0 + ty + r) * 2048 + k0 + tx] = (f16)tile[tx][ty + r];
}

// ---- 8-wave 256xBN MFMA GEMM, split-issue counted-vmcnt schedule ----
// C[M,N] = A[M,K] * BT[N,K]^T. 512 threads = 8 waves (2M x 4N), 128 x BN/4 out/wave.
// Next tile: B*+A0+A2 issued at p0, A1+A3 at p2. Boundary waits vmcnt(2) (late A
// pair rides across); mid-tile vmcnt(BI+2)+barrier publishes the late pair before
// p2's ds_reads. vmcnt retires in order (m135), so counts identify batches.
template <int BN_, int N_, bool OUT_F16>
__global__ __launch_bounds__(512, 2) void k_gemm8(const f16* __restrict__ A,
                                                  const f16* __restrict__ BT,
                                                  void* __restrict__ Cp, int M, int K) {
  constexpr int NF = BN_ / 64;   // 16-col B-fragments per wave
  constexpr int BI = BN_ / 64;   // B staging issues (64 rows each)
  constexpr int MIDN = BI + 2;   // mid-wait: allow next tile's p0 batch outstanding
  __shared__ alignas(16) char Abuf[2][256 * 128];  // 256 rows x 128B, linear
  __shared__ alignas(16) char Bbuf[2][BN_ * 128];
  constexpr int NT = N_ / BN_;
  // T1: XCD-aware bijective remap (grid % 8 == 0)
  int bid0 = blockIdx.x;
  int bid = (bid0 & 7) * (gridDim.x >> 3) + (bid0 >> 3);
  int m0 = (bid / NT) * 256, n0 = (bid % NT) * BN_;
  int tid = threadIdx.x;
  int lane = tid & 63, w = tid >> 6;
  int wr = w >> 2, wc = w & 3;
  int g = lane >> 4, c = lane & 15;
  int rswz = (c & 7) << 4;  // read-side XOR (fragment row&7 == c&7)

  int srow = tid >> 3;                     // 0..63 within issue
  int scbs = ((tid & 7) * 16) ^ ((srow & 7) << 4);
  const char* Ag = (const char*)A + (size_t)(m0 + srow) * (K * 2) + scbs;
  const char* Bg = (const char*)BT + (size_t)(n0 + srow) * (K * 2) + scbs;
  int lbase = w * 1024;  // wave-uniform LDS base; HW adds lane*16

  f32x4 acc[8][NF] = {};
  int nk = K >> 6;

  auto stageA = [&](int buf, int kt, int i) {
    gload16(Ag + (size_t)(i * 64) * (K * 2) + (size_t)kt * 128,
            &Abuf[buf][i * 8192 + lbase]);
  };
  auto stageB = [&](int buf, int kt, int i) {
    gload16(Bg + (size_t)(i * 64) * (K * 2) + (size_t)kt * 128,
            &Bbuf[buf][i * 8192 + lbase]);
  };

  // prologue: stage K-tile 0 into buf 0, drain, publish
  {
#pragma unroll
    for (int i = 0; i < 4; i++) stageA(0, 0, i);
#pragma unroll
    for (int i = 0; i < BI; i++) stageB(0, 0, i);
    waitvm<0>();
    __builtin_amdgcn_s_barrier();
  }

  for (int kt = 0; kt < nk; kt++) {
    int cur = kt & 1, nxt = cur ^ 1;
    bool more = (kt + 1) < nk;
    const char* Ab = Abuf[cur];
    const char* Bb = Bbuf[cur];
    f16x8 bf[NF][2], af[2][2];
#pragma unroll
    for (int p = 0; p < 4; p++) {
      if (p == 0) {
#pragma unroll
        for (int nn = 0; nn < NF; nn++)
#pragma unroll
          for (int kk = 0; kk < 2; kk++) {
            int R = wc * (NF * 16) + nn * 16 + c;
            bf[nn][kk] = *(const f16x8*)(Bb + R * 128 + ((kk * 64 + g * 16) ^ rswz));
          }
      }
#pragma unroll
      for (int j = 0; j < 2; j++)
#pragma unroll
        for (int kk = 0; kk < 2; kk++) {
          int R = wr * 128 + (p * 2 + j) * 16 + c;
          af[j][kk] = *(const f16x8*)(Ab + R * 128 + ((kk * 64 + g * 16) ^ rswz));
        }
      if (more) {
        if (p == 0) {  // early batch: all B + A issues 0,2 (needed at kt+1 p0/p1)
#pragma unroll
          for (int i = 0; i < BI; i++) stageB(nxt, kt + 1, i);
          stageA(nxt, kt + 1, 0); stageA(nxt, kt + 1, 2);
        } else if (p == 2) {  // late batch: A issues 1,3 (needed at kt+1 p2)
          stageA(nxt, kt + 1, 1); stageA(nxt, kt + 1, 3);
        }
      }
      __builtin_amdgcn_s_barrier();
      __builtin_amdgcn_s_setprio(1);
#pragma unroll
      for (int j = 0; j < 2; j++)
#pragma unroll
        for (int nn = 0; nn < NF; nn++)
#pragma unroll
          for (int kk = 0; kk < 2; kk++)
            acc[p * 2 + j][nn] = MFMA16(af[j][kk], bf[nn][kk], acc[p * 2 + j][nn]);
      __builtin_amdgcn_s_setprio(0);
      if (p == 1) {
        // publish THIS tile's late A pair (issued last tile p2) before p2 reads
        if (more) waitvm<MIDN>(); else waitvm<0>();
        __builtin_amdgcn_s_barrier();
      }
    }
    // boundary: next tile's early batch must have landed; its late pair may ride
    if (more) waitvm<2>(); else waitvm<0>();
    __builtin_amdgcn_s_barrier();
  }
  // epilogue: C-write
#pragma unroll
  for (int mm = 0; mm < 8; mm++)
#pragma unroll
    for (int nn = 0; nn < NF; nn++)
#pragma unroll
      for (int r = 0; r < 4; r++) {
        size_t row = m0 + wr * 128 + mm * 16 + g * 4 + r;
        size_t col = n0 + wc * (NF * 16) + nn * 16 + c;
        float v = acc[mm][nn][r];
        if constexpr (OUT_F16)
          ((f16*)Cp)[row * N_ + col] = (f16)v;
        else
          ((float*)Cp)[row * N_ + col] = v;
      }
}

// ---- post-QKV: RMSNorm+RoPE (Q,K) and V transpose, one launch ----
__global__ __launch_bounds__(256) void k_post(const f16* __restrict__ qkv,
                                              const int* __restrict__ pos_ids,
                                              const float* __restrict__ qw,
                                              const float* __restrict__ kw,
                                              f16* __restrict__ Qo, f16* __restrict__ Ko,
                                              f16* __restrict__ Vt) {
  int blk = blockIdx.x;
  int tid = threadIdx.x;
  if (blk < 4096) {  // norm+rope
    int bt = blk;
    int b = bt >> 11, t = bt & 2047;
    int w = tid >> 6, lane = tid & 63;
    const f16* row = qkv + (size_t)bt * 3072;
    float pq = (float)pos_ids[t];
    float pk = (float)t;
    float inv = expf(-(float)lane * 0.14391156831212787f);
    float aq = pq * inv, ak = pk * inv;
    float snq = sinf(aq), csq = cosf(aq);
    float snk = sinf(ak), csk = cosf(ak);
    for (int hi = w; hi < 20; hi += 4) {
      bool isq = hi < 16;
      int off = isq ? hi * 128 : 2048 + (hi - 16) * 128;
      float x1 = (float)row[off + 2 * lane];
      float x2 = (float)row[off + 2 * lane + 1];
      float ss = x1 * x1 + x2 * x2;
#pragma unroll
      for (int o = 1; o < 64; o <<= 1) ss += __shfl_xor(ss, o);
      float rms = rsqrtf(ss * (1.0f / 128.0f) + 1e-6f);
      const float* wt = isq ? qw : kw;
      float n1 = x1 * rms * wt[2 * lane], n2 = x2 * rms * wt[2 * lane + 1];
      float sn = isq ? snq : snk, cs = isq ? csq : csk;
      f16 r1 = (f16)(n1 * cs - n2 * sn), r2 = (f16)(n1 * sn + n2 * cs);
      if (isq) {
        f16* dst = Qo + (((size_t)b * HQ + hi) * TT + t) * HD;
        dst[2 * lane] = r1;
        dst[2 * lane + 1] = r2;
      } else {
        f16* dst = Ko + (((size_t)b * HKV + (hi - 16)) * TT + t) * HD;
        dst[2 * lane] = r1;
        dst[2 * lane + 1] = r2;
      }
    }
    return;
  }
  // V transpose: Vt[b][hkv][d][t]
  __shared__ f16 tile[32][34];
  int t2 = blk - 4096;
  int t0 = (t2 & 63) * 32, d0 = ((t2 >> 6) & 3) * 32;
  int bh = t2 >> 8;
  int b = bh >> 2, hkv = bh & 3;
  int tx = tid & 31, ty = tid >> 5;
  const f16* src = qkv + (size_t)b * 2048 * 3072 + 2560 + hkv * 128;
#pragma unroll
  for (int r = 0; r < 32; r += 8)
    tile[ty + r][tx] = src[(size_t)(t0 + ty + r) * 3072 + d0 + tx];
  __syncthreads();
  f16* dst = Vt + ((size_t)bh * HD + d0) * TT + t0;
#pragma unroll
  for (int r = 0; r < 32; r += 8)
    dst[(size_t)(ty + r) * TT + tx] = tile[tx][ty + r];
}

// ---- attention: 4 waves x 32q, 64-key tiles, swapped QK^T, gload_lds dbuf staging ----
__global__ __launch_bounds__(256, 2) void k_attn2(const f16* __restrict__ Q,
                                                  const f16* __restrict__ Kc,
                                                  const f16* __restrict__ Vt,
                                                  f16* __restrict__ Oa) {
  __shared__ alignas(16) char KsC[2][64 * 256];   // K: 64 keys x 128 d (256B rows)
  __shared__ alignas(16) char VsC[2][128 * 128];  // V^T: 128 d x 64 keys (128B rows)
  int qt = blockIdx.x, h = blockIdx.y, b = blockIdx.z;
  // balance remap (r11, measured best): blocks i and i+256 share a CU and differ
  // only in b -> pair (qt, 15-qt)
  qt = b ? (15 - qt) : qt;
  int q0 = qt * 128, hkv = h >> 2;
  int tid = threadIdx.x;
  int w = tid >> 6, lane = tid & 63, ln = lane & 31, hi = lane >> 5;
  const char* KbB = (const char*)(Kc + ((size_t)b * HKV + hkv) * TT * HD);
  const char* VbB = (const char*)(Vt + ((size_t)b * HKV + hkv) * (size_t)HD * TT);
  int q = q0 + w * 32 + ln;
  const f16* Qp = Q + (((size_t)b * HQ + h) * TT + q) * HD + hi * 8;
  f16x8 qf[8];
#pragma unroll
  for (int st = 0; st < 8; st++) qf[st] = *(const f16x8*)&Qp[st * 16];
  f32x16 o[4] = {};
  float lsum = 0.f;
  int kfswz = (ln & 7) << 4;

  int krow0 = w * 4 + (lane >> 4);
  int kswzb = ((lane & 15) * 16) ^ ((krow0 & 7) << 4);
  int vrow0 = w * 8 + (lane >> 3);
  int vswzb = ((lane & 7) * 16) ^ ((vrow0 & 7) << 4);

  int k0max = (q0 + 127) & ~63;
  int wlo = (q0 - 1023 > 128) ? ((q0 - 1023) & ~63) : 128;
  int nw = (k0max >= wlo) ? ((k0max - wlo) >> 6) + 1 : 0;
  int ntiles = 2 + nw;
  int qw = q0 + w * 32;

  const float C1 = 0.12751791217100872f;  // (1/sqrt(128)) * log2(e)
  const float C2 = 5.7707801635534255f;   // 4.0 * log2(e)  (fixed softmax shift)

  auto stage = [&](int buf, int k0) {
    const char* ks = KbB + (size_t)(k0 + krow0) * 256 + kswzb;
    const char* vs = VbB + (size_t)vrow0 * (TT * 2) + (size_t)k0 * 2 + vswzb;
    char* kd = KsC[buf] + w * 1024;
    char* vd = VsC[buf] + w * 1024;
#pragma unroll
    for (int j = 0; j < 4; j++) gload16(ks + (size_t)j * 4096, kd + j * 4096);
#pragma unroll
    for (int j = 0; j < 4; j++) gload16(vs + (size_t)j * 32 * (TT * 2), vd + j * 4096);
  };

  stage(0, 0);
  __syncthreads();
  int cur = 0;

  for (int ti = 0; ti < ntiles; ti++) {
    int k0 = (ti < 2) ? ti * 64 : wlo + (ti - 2) * 64;
    bool havenext = (ti + 1 < ntiles);
    if (havenext) {
      int k0n = (ti + 1 < 2) ? 64 : wlo + (ti - 1) * 64;
      stage(cur ^ 1, k0n);
    }
    bool needmask = false;
    if (ti >= 2) {
      int wsmax = qw + 31 - 1023;
      if (wsmax < 128) wsmax = 128;
      needmask = !((k0 + 63 <= qw) && (k0 >= wsmax));
    }
    f16x8 pa[2][2];
#pragma unroll
    for (int ksub = 0; ksub < 2; ksub++) {
      f32x16 s0 = {}, s1 = {};
      const char* krow = KsC[cur] + (ksub * 32 + ln) * 256;
      __builtin_amdgcn_s_setprio(1);
#pragma unroll
      for (int st = 0; st < 8; st += 2) {
        f16x8 kf0 = *(const f16x8*)(krow + ((st * 32 + hi * 16) ^ kfswz));
        f16x8 kf1 = *(const f16x8*)(krow + (((st + 1) * 32 + hi * 16) ^ kfswz));
        s0 = MFMA32(kf0, qf[st], s0);
        s1 = MFMA32(kf1, qf[st + 1], s1);
      }
      __builtin_amdgcn_s_setprio(0);
      f32x16 s = s0 + s1;
      int qmk = q - (k0 + ksub * 32 + 4 * hi);
      float pr[16];
#pragma unroll
      for (int r = 0; r < 16; r++) {
        float e = fast_exp2(s[r] * C1 - C2);
        if (needmask) {
          int kk = (r & 3) + 8 * (r >> 2);
          e = ((uint32_t)(qmk - kk) < 1024u) ? e : 0.0f;
        }
        lsum += e;
        pr[r] = e;
      }
      uint32_t c[8];
#pragma unroll
      for (int i = 0; i < 8; i++) c[i] = cvt_pk_u32(pr[2 * i], pr[2 * i + 1]);
      {
        uint32_t x0 = __shfl_xor(c[0], 32), x1 = __shfl_xor(c[1], 32);
        uint32_t x2 = __shfl_xor(c[2], 32), x3 = __shfl_xor(c[3], 32);
        u32x4 t0 = {hi ? x2 : c[0], hi ? x3 : c[1], hi ? c[2] : x0, hi ? c[3] : x1};
        pa[ksub][0] = __builtin_bit_cast(f16x8, t0);
        uint32_t x4 = __shfl_xor(c[4], 32), x5 = __shfl_xor(c[5], 32);
        uint32_t x6 = __shfl_xor(c[6], 32), x7 = __shfl_xor(c[7], 32);
        u32x4 t1 = {hi ? x6 : c[4], hi ? x7 : c[5], hi ? c[6] : x4, hi ? c[7] : x5};
        pa[ksub][1] = __builtin_bit_cast(f16x8, t1);
      }
    }
    __builtin_amdgcn_s_setprio(1);
#pragma unroll
    for (int dsub = 0; dsub < 4; dsub++) {
      const char* vrow = VsC[cur] + (dsub * 32 + ln) * 128;
#pragma unroll
      for (int ksub = 0; ksub < 2; ksub++)
#pragma unroll
        for (int st2 = 0; st2 < 2; st2++) {
          f16x8 vf = *(const f16x8*)(vrow + ((ksub * 64 + st2 * 32 + hi * 16) ^ kfswz));
          o[dsub] = MFMA32(pa[ksub][st2], vf, o[dsub]);
        }
    }
    __builtin_amdgcn_s_setprio(0);
    __syncthreads();
    cur ^= 1;
  }
  // epilogue: finish l, scale, store
  lsum += __shfl_xor(lsum, 32);
  float rl[16];
#pragma unroll
  for (int r = 0; r < 16; r++) {
    int row = (r & 3) + 8 * (r >> 2) + 4 * hi;
    float lv = __shfl(lsum, row);
    rl[r] = 1.0f / lv;
  }
#pragma unroll
  for (int r = 0; r < 16; r++) {
    int row = (r & 3) + 8 * (r >> 2) + 4 * hi;
    size_t base = ((size_t)b * TT + q0 + w * 32 + row) * DM + (size_t)h * HD + ln;
#pragma unroll
    for (int dsub = 0; dsub < 4; dsub++)
      Oa[base + dsub * 32] = (f16)(o[dsub][r] * rl[r]);
  }
}

extern "C" void kernel_launch(void* const* d_in, const int* in_sizes, int n_in,
                              void* d_out, int out_size, void* d_ws, size_t ws_size,
                              hipStream_t stream) {
  const float* hidden = (const float*)d_in[0];
  const int* pos = (const int*)d_in[1];
  const float* Wq = (const float*)d_in[2];
  const float* Wk = (const float*)d_in[3];
  const float* Wv = (const float*)d_in[4];
  const float* Wo = (const float*)d_in[5];
  const float* qw = (const float*)d_in[6];
  const float* kw = (const float*)d_in[7];
  float* out = (float*)d_out;

  char* p = (char*)d_ws;
  auto take = [&](size_t n) {
    void* r = (void*)p;
    p += (n + 255) & ~(size_t)255;
    return r;
  };
  f16* Xb = (f16*)take((size_t)4096 * 2048 * 2);
  f16* WqkvT = (f16*)take((size_t)3072 * 2048 * 2);
  f16* WoT = (f16*)take((size_t)2048 * 2048 * 2);
  f16* QKVb = (f16*)take((size_t)4096 * 3072 * 2);
  f16* Qr = (f16*)take((size_t)BB * HQ * TT * HD * 2);
  f16* Kr = (f16*)take((size_t)BB * HKV * TT * HD * 2);
  f16* Vt = (f16*)take((size_t)BB * HKV * TT * HD * 2);
  f16* Attn = (f16*)take((size_t)4096 * 2048 * 2);

  k_prep<<<14336, 256, 0, stream>>>(hidden, Wq, Wk, Wv, Wo, Xb, WqkvT, WoT);
  k_gemm8<256, 3072, true><<<192, 512, 0, stream>>>(Xb, WqkvT, QKVb, 4096, 2048);
  k_post<<<6144, 256, 0, stream>>>(QKVb, pos, qw, kw, Qr, Kr, Vt);
  k_attn2<<<dim3(16, 16, 2), 256, 0, stream>>>(Qr, Kr, Vt, Attn);
  k_gemm8<128, 2048, false><<<256, 512, 0, stream>>>(Attn, WoT, out, 4096, 2048);
}

// Round 16
// 191.195 us; speedup vs baseline: 1.0359x; 1.0359x over previous
//
#include <hip/hip_runtime.h>
#include <cstdint>
#include <cstddef>

#define DM 2048
#define TT 2048
#define BB 2
#define HQ 16
#define HKV 4
#define HD 128

typedef _Float16 f16;
using f16x8 = __attribute__((ext_vector_type(8))) f16;
using f32x4 = __attribute__((ext_vector_type(4))) float;
using f32x16 = __attribute__((ext_vector_type(16))) float;
using u32x4 = __attribute__((ext_vector_type(4))) uint32_t;

#define MFMA16(a, b, c) __builtin_amdgcn_mfma_f32_16x16x32_f16(a, b, c, 0, 0, 0)
#define MFMA32(a, b, c) __builtin_amdgcn_mfma_f32_32x32x16_f16(a, b, c, 0, 0, 0)

typedef __attribute__((address_space(1))) const void gvoid_t;
typedef __attribute__((address_space(3))) void lvoid_t;
static __device__ __forceinline__ void gload16(const void* g, void* l) {
  __builtin_amdgcn_global_load_lds((gvoid_t*)g, (lvoid_t*)l, 16, 0, 0);
}

template <int N>
static __device__ __forceinline__ void waitvm() {
  if constexpr (N == 0) asm volatile("s_waitcnt vmcnt(0)" ::: "memory");
  else if constexpr (N == 2) asm volatile("s_waitcnt vmcnt(2)" ::: "memory");
  else if constexpr (N == 4) asm volatile("s_waitcnt vmcnt(4)" ::: "memory");
  else if constexpr (N == 5) asm volatile("s_waitcnt vmcnt(5)" ::: "memory");
  else if constexpr (N == 6) asm volatile("s_waitcnt vmcnt(6)" ::: "memory");
}

static __device__ __forceinline__ float fast_exp2(float x) {
#if __has_builtin(__builtin_amdgcn_exp2f)
  return __builtin_amdgcn_exp2f(x);
#else
  return exp2f(x);
#endif
}

static __device__ __forceinline__ uint32_t cvt_pk_u32(float a, float b) {
  auto h2 = __builtin_amdgcn_cvt_pkrtz(a, b);
  return __builtin_bit_cast(uint32_t, h2);
}

// ---- prep: fp32->f16 convert of hidden  +  all weight transposes, one launch ----
__global__ __launch_bounds__(256) void k_prep(const float* __restrict__ hidden,
                                              const float* __restrict__ Wq,
                                              const float* __restrict__ Wk,
                                              const float* __restrict__ Wv,
                                              const float* __restrict__ Wo,
                                              f16* __restrict__ Xb,
                                              f16* __restrict__ WqkvT,
                                              f16* __restrict__ WoT) {
  int t = blockIdx.x;
  int tid = threadIdx.x;
  if (t < 4096) {  // convert: 8 floats per thread
    int i = t * 256 + tid;
    const float4* pin = (const float4*)hidden;
    float4 a = pin[2 * i], b = pin[2 * i + 1];
    f16x8 o = {(f16)a.x, (f16)a.y, (f16)a.z, (f16)a.w,
               (f16)b.x, (f16)b.y, (f16)b.z, (f16)b.w};
    *(f16x8*)&Xb[(size_t)8 * i] = o;
    return;
  }
  __shared__ float tile[32][33];
  t -= 4096;
  const float* in;
  f16* out;
  int N, nx;
  if (t < 4096) {
    in = Wq; out = WqkvT; N = 2048; nx = 64;
  } else if (t < 5120) {
    t -= 4096; in = Wk; out = WqkvT + (size_t)2048 * 2048; N = 512; nx = 16;
  } else if (t < 6144) {
    t -= 5120; in = Wv; out = WqkvT + (size_t)2560 * 2048; N = 512; nx = 16;
  } else {
    t -= 6144; in = Wo; out = WoT; N = 2048; nx = 64;
  }
  int n0 = (t % nx) * 32, k0 = (t / nx) * 32;
  int tx = tid & 31, ty = tid >> 5;
#pragma unroll
  for (int r = 0; r < 32; r += 8) tile[ty + r][tx] = in[(size_t)(k0 + ty + r) * N + n0 + tx];
  __syncthreads();
#pragma unroll
  for (int r = 0; r < 32; r += 8)
    out[(size_t)(n0 + ty + r) * 2048 + k0 + tx] = (f16)tile[tx][ty + r];
}

// ---- 8-wave 256xBN MFMA GEMM, split-issue counted-vmcnt schedule ----
// C[M,N] = A[M,K] * BT[N,K]^T. 512 threads = 8 waves (2M x 4N), 128 x BN/4 out/wave.
// Next tile: B*+A0+A2 issued at p0, A1+A3 at p2. Boundary waits vmcnt(2) (late A
// pair rides across); mid-tile vmcnt(BI+2)+barrier publishes the late pair before
// p2's ds_reads. vmcnt retires in order (m135), so counts identify batches.
template <int BN_, int N_, bool OUT_F16>
__global__ __launch_bounds__(512, 2) void k_gemm8(const f16* __restrict__ A,
                                                  const f16* __restrict__ BT,
                                                  void* __restrict__ Cp, int M, int K) {
  constexpr int NF = BN_ / 64;   // 16-col B-fragments per wave
  constexpr int BI = BN_ / 64;   // B staging issues (64 rows each)
  constexpr int MIDN = BI + 2;   // mid-wait: allow next tile's p0 batch outstanding
  __shared__ alignas(16) char Abuf[2][256 * 128];  // 256 rows x 128B, linear
  __shared__ alignas(16) char Bbuf[2][BN_ * 128];
  constexpr int NT = N_ / BN_;
  // T1: XCD-aware bijective remap (grid % 8 == 0)
  int bid0 = blockIdx.x;
  int bid = (bid0 & 7) * (gridDim.x >> 3) + (bid0 >> 3);
  int m0 = (bid / NT) * 256, n0 = (bid % NT) * BN_;
  int tid = threadIdx.x;
  int lane = tid & 63, w = tid >> 6;
  int wr = w >> 2, wc = w & 3;
  int g = lane >> 4, c = lane & 15;
  int rswz = (c & 7) << 4;  // read-side XOR (fragment row&7 == c&7)

  int srow = tid >> 3;                     // 0..63 within issue
  int scbs = ((tid & 7) * 16) ^ ((srow & 7) << 4);
  const char* Ag = (const char*)A + (size_t)(m0 + srow) * (K * 2) + scbs;
  const char* Bg = (const char*)BT + (size_t)(n0 + srow) * (K * 2) + scbs;
  int lbase = w * 1024;  // wave-uniform LDS base; HW adds lane*16

  f32x4 acc[8][NF] = {};
  int nk = K >> 6;

  auto stageA = [&](int buf, int kt, int i) {
    gload16(Ag + (size_t)(i * 64) * (K * 2) + (size_t)kt * 128,
            &Abuf[buf][i * 8192 + lbase]);
  };
  auto stageB = [&](int buf, int kt, int i) {
    gload16(Bg + (size_t)(i * 64) * (K * 2) + (size_t)kt * 128,
            &Bbuf[buf][i * 8192 + lbase]);
  };

  // prologue: stage K-tile 0 into buf 0, drain, publish
  {
#pragma unroll
    for (int i = 0; i < 4; i++) stageA(0, 0, i);
#pragma unroll
    for (int i = 0; i < BI; i++) stageB(0, 0, i);
    waitvm<0>();
    __builtin_amdgcn_s_barrier();
  }

  for (int kt = 0; kt < nk; kt++) {
    int cur = kt & 1, nxt = cur ^ 1;
    bool more = (kt + 1) < nk;
    const char* Ab = Abuf[cur];
    const char* Bb = Bbuf[cur];
    f16x8 bf[NF][2], af[2][2];
#pragma unroll
    for (int p = 0; p < 4; p++) {
      if (p == 0) {
#pragma unroll
        for (int nn = 0; nn < NF; nn++)
#pragma unroll
          for (int kk = 0; kk < 2; kk++) {
            int R = wc * (NF * 16) + nn * 16 + c;
            bf[nn][kk] = *(const f16x8*)(Bb + R * 128 + ((kk * 64 + g * 16) ^ rswz));
          }
      }
#pragma unroll
      for (int j = 0; j < 2; j++)
#pragma unroll
        for (int kk = 0; kk < 2; kk++) {
          int R = wr * 128 + (p * 2 + j) * 16 + c;
          af[j][kk] = *(const f16x8*)(Ab + R * 128 + ((kk * 64 + g * 16) ^ rswz));
        }
      if (more) {
        if (p == 0) {  // early batch: all B + A issues 0,2 (needed at kt+1 p0/p1)
#pragma unroll
          for (int i = 0; i < BI; i++) stageB(nxt, kt + 1, i);
          stageA(nxt, kt + 1, 0); stageA(nxt, kt + 1, 2);
        } else if (p == 2) {  // late batch: A issues 1,3 (needed at kt+1 p2)
          stageA(nxt, kt + 1, 1); stageA(nxt, kt + 1, 3);
        }
      }
      __builtin_amdgcn_s_barrier();
      __builtin_amdgcn_s_setprio(1);
#pragma unroll
      for (int j = 0; j < 2; j++)
#pragma unroll
        for (int nn = 0; nn < NF; nn++)
#pragma unroll
          for (int kk = 0; kk < 2; kk++)
            acc[p * 2 + j][nn] = MFMA16(af[j][kk], bf[nn][kk], acc[p * 2 + j][nn]);
      __builtin_amdgcn_s_setprio(0);
      if (p == 1) {
        // publish THIS tile's late A pair (issued last tile p2) before p2 reads
        if (more) waitvm<MIDN>(); else waitvm<0>();
        __builtin_amdgcn_s_barrier();
      }
    }
    // boundary: next tile's early batch must have landed; its late pair may ride
    if (more) waitvm<2>(); else waitvm<0>();
    __builtin_amdgcn_s_barrier();
  }
  // epilogue: C-write
#pragma unroll
  for (int mm = 0; mm < 8; mm++)
#pragma unroll
    for (int nn = 0; nn < NF; nn++)
#pragma unroll
      for (int r = 0; r < 4; r++) {
        size_t row = m0 + wr * 128 + mm * 16 + g * 4 + r;
        size_t col = n0 + wc * (NF * 16) + nn * 16 + c;
        float v = acc[mm][nn][r];
        if constexpr (OUT_F16)
          ((f16*)Cp)[row * N_ + col] = (f16)v;
        else
          ((float*)Cp)[row * N_ + col] = v;
      }
}

// ---- post-QKV: RMSNorm+RoPE (Q,K) and V transpose, one launch ----
__global__ __launch_bounds__(256) void k_post(const f16* __restrict__ qkv,
                                              const int* __restrict__ pos_ids,
                                              const float* __restrict__ qw,
                                              const float* __restrict__ kw,
                                              f16* __restrict__ Qo, f16* __restrict__ Ko,
                                              f16* __restrict__ Vt) {
  int blk = blockIdx.x;
  int tid = threadIdx.x;
  if (blk < 4096) {  // norm+rope
    int bt = blk;
    int b = bt >> 11, t = bt & 2047;
    int w = tid >> 6, lane = tid & 63;
    const f16* row = qkv + (size_t)bt * 3072;
    float pq = (float)pos_ids[t];
    float pk = (float)t;
    float inv = expf(-(float)lane * 0.14391156831212787f);
    float aq = pq * inv, ak = pk * inv;
    float snq = sinf(aq), csq = cosf(aq);
    float snk = sinf(ak), csk = cosf(ak);
    for (int hi = w; hi < 20; hi += 4) {
      bool isq = hi < 16;
      int off = isq ? hi * 128 : 2048 + (hi - 16) * 128;
      float x1 = (float)row[off + 2 * lane];
      float x2 = (float)row[off + 2 * lane + 1];
      float ss = x1 * x1 + x2 * x2;
#pragma unroll
      for (int o = 1; o < 64; o <<= 1) ss += __shfl_xor(ss, o);
      float rms = rsqrtf(ss * (1.0f / 128.0f) + 1e-6f);
      const float* wt = isq ? qw : kw;
      float n1 = x1 * rms * wt[2 * lane], n2 = x2 * rms * wt[2 * lane + 1];
      float sn = isq ? snq : snk, cs = isq ? csq : csk;
      f16 r1 = (f16)(n1 * cs - n2 * sn), r2 = (f16)(n1 * sn + n2 * cs);
      if (isq) {
        f16* dst = Qo + (((size_t)b * HQ + hi) * TT + t) * HD;
        dst[2 * lane] = r1;
        dst[2 * lane + 1] = r2;
      } else {
        f16* dst = Ko + (((size_t)b * HKV + (hi - 16)) * TT + t) * HD;
        dst[2 * lane] = r1;
        dst[2 * lane + 1] = r2;
      }
    }
    return;
  }
  // V transpose: Vt[b][hkv][d][t]
  __shared__ f16 tile[32][34];
  int t2 = blk - 4096;
  int t0 = (t2 & 63) * 32, d0 = ((t2 >> 6) & 3) * 32;
  int bh = t2 >> 8;
  int b = bh >> 2, hkv = bh & 3;
  int tx = tid & 31, ty = tid >> 5;
  const f16* src = qkv + (size_t)b * 2048 * 3072 + 2560 + hkv * 128;
#pragma unroll
  for (int r = 0; r < 32; r += 8)
    tile[ty + r][tx] = src[(size_t)(t0 + ty + r) * 3072 + d0 + tx];
  __syncthreads();
  f16* dst = Vt + ((size_t)bh * HD + d0) * TT + t0;
#pragma unroll
  for (int r = 0; r < 32; r += 8)
    dst[(size_t)(ty + r) * TT + tx] = tile[tx][ty + r];
}

// ---- attention: 4 waves x 32q, 64-key tiles, swapped QK^T, gload_lds dbuf staging ----
__global__ __launch_bounds__(256, 2) void k_attn2(const f16* __restrict__ Q,
                                                  const f16* __restrict__ Kc,
                                                  const f16* __restrict__ Vt,
                                                  f16* __restrict__ Oa) {
  __shared__ alignas(16) char KsC[2][64 * 256];   // K: 64 keys x 128 d (256B rows)
  __shared__ alignas(16) char VsC[2][128 * 128];  // V^T: 128 d x 64 keys (128B rows)
  int qt = blockIdx.x, h = blockIdx.y, b = blockIdx.z;
  // balance remap (r11, measured best): blocks i and i+256 share a CU and differ
  // only in b -> pair (qt, 15-qt)
  qt = b ? (15 - qt) : qt;
  int q0 = qt * 128, hkv = h >> 2;
  int tid = threadIdx.x;
  int w = tid >> 6, lane = tid & 63, ln = lane & 31, hi = lane >> 5;
  const char* KbB = (const char*)(Kc + ((size_t)b * HKV + hkv) * TT * HD);
  const char* VbB = (const char*)(Vt + ((size_t)b * HKV + hkv) * (size_t)HD * TT);
  int q = q0 + w * 32 + ln;
  const f16* Qp = Q + (((size_t)b * HQ + h) * TT + q) * HD + hi * 8;
  f16x8 qf[8];
#pragma unroll
  for (int st = 0; st < 8; st++) qf[st] = *(const f16x8*)&Qp[st * 16];
  f32x16 o[4] = {};
  float lsum = 0.f;
  int kfswz = (ln & 7) << 4;

  int krow0 = w * 4 + (lane >> 4);
  int kswzb = ((lane & 15) * 16) ^ ((krow0 & 7) << 4);
  int vrow0 = w * 8 + (lane >> 3);
  int vswzb = ((lane & 7) * 16) ^ ((vrow0 & 7) << 4);

  int k0max = (q0 + 127) & ~63;
  int wlo = (q0 - 1023 > 128) ? ((q0 - 1023) & ~63) : 128;
  int nw = (k0max >= wlo) ? ((k0max - wlo) >> 6) + 1 : 0;
  int ntiles = 2 + nw;
  int qw = q0 + w * 32;

  const float C1 = 0.12751791217100872f;  // (1/sqrt(128)) * log2(e)
  const float C2 = 5.7707801635534255f;   // 4.0 * log2(e)  (fixed softmax shift)

  auto stage = [&](int buf, int k0) {
    const char* ks = KbB + (size_t)(k0 + krow0) * 256 + kswzb;
    const char* vs = VbB + (size_t)vrow0 * (TT * 2) + (size_t)k0 * 2 + vswzb;
    char* kd = KsC[buf] + w * 1024;
    char* vd = VsC[buf] + w * 1024;
#pragma unroll
    for (int j = 0; j < 4; j++) gload16(ks + (size_t)j * 4096, kd + j * 4096);
#pragma unroll
    for (int j = 0; j < 4; j++) gload16(vs + (size_t)j * 32 * (TT * 2), vd + j * 4096);
  };

  stage(0, 0);
  __syncthreads();
  int cur = 0;

  for (int ti = 0; ti < ntiles; ti++) {
    int k0 = (ti < 2) ? ti * 64 : wlo + (ti - 2) * 64;
    bool havenext = (ti + 1 < ntiles);
    if (havenext) {
      int k0n = (ti + 1 < 2) ? 64 : wlo + (ti - 1) * 64;
      stage(cur ^ 1, k0n);
    }
    bool needmask = false;
    if (ti >= 2) {
      int wsmax = qw + 31 - 1023;
      if (wsmax < 128) wsmax = 128;
      needmask = !((k0 + 63 <= qw) && (k0 >= wsmax));
    }
    f16x8 pa[2][2];
#pragma unroll
    for (int ksub = 0; ksub < 2; ksub++) {
      f32x16 s0 = {}, s1 = {};
      const char* krow = KsC[cur] + (ksub * 32 + ln) * 256;
      __builtin_amdgcn_s_setprio(1);
#pragma unroll
      for (int st = 0; st < 8; st += 2) {
        f16x8 kf0 = *(const f16x8*)(krow + ((st * 32 + hi * 16) ^ kfswz));
        f16x8 kf1 = *(const f16x8*)(krow + (((st + 1) * 32 + hi * 16) ^ kfswz));
        s0 = MFMA32(kf0, qf[st], s0);
        s1 = MFMA32(kf1, qf[st + 1], s1);
      }
      __builtin_amdgcn_s_setprio(0);
      f32x16 s = s0 + s1;
      int qmk = q - (k0 + ksub * 32 + 4 * hi);
      float pr[16];
#pragma unroll
      for (int r = 0; r < 16; r++) {
        float e = fast_exp2(s[r] * C1 - C2);
        if (needmask) {
          int kk = (r & 3) + 8 * (r >> 2);
          e = ((uint32_t)(qmk - kk) < 1024u) ? e : 0.0f;
        }
        lsum += e;
        pr[r] = e;
      }
      uint32_t c[8];
#pragma unroll
      for (int i = 0; i < 8; i++) c[i] = cvt_pk_u32(pr[2 * i], pr[2 * i + 1]);
      {
        uint32_t x0 = __shfl_xor(c[0], 32), x1 = __shfl_xor(c[1], 32);
        uint32_t x2 = __shfl_xor(c[2], 32), x3 = __shfl_xor(c[3], 32);
        u32x4 t0 = {hi ? x2 : c[0], hi ? x3 : c[1], hi ? c[2] : x0, hi ? c[3] : x1};
        pa[ksub][0] = __builtin_bit_cast(f16x8, t0);
        uint32_t x4 = __shfl_xor(c[4], 32), x5 = __shfl_xor(c[5], 32);
        uint32_t x6 = __shfl_xor(c[6], 32), x7 = __shfl_xor(c[7], 32);
        u32x4 t1 = {hi ? x6 : c[4], hi ? x7 : c[5], hi ? c[6] : x4, hi ? c[7] : x5};
        pa[ksub][1] = __builtin_bit_cast(f16x8, t1);
      }
    }
    __builtin_amdgcn_s_setprio(1);
#pragma unroll
    for (int dsub = 0; dsub < 4; dsub++) {
      const char* vrow = VsC[cur] + (dsub * 32 + ln) * 128;
#pragma unroll
      for (int ksub = 0; ksub < 2; ksub++)
#pragma unroll
        for (int st2 = 0; st2 < 2; st2++) {
          f16x8 vf = *(const f16x8*)(vrow + ((ksub * 64 + st2 * 32 + hi * 16) ^ kfswz));
          o[dsub] = MFMA32(pa[ksub][st2], vf, o[dsub]);
        }
    }
    __builtin_amdgcn_s_setprio(0);
    __syncthreads();
    cur ^= 1;
  }
  // epilogue: finish l, scale, store
  lsum += __shfl_xor(lsum, 32);
  float rl[16];
#pragma unroll
  for (int r = 0; r < 16; r++) {
    int row = (r & 3) + 8 * (r >> 2) + 4 * hi;
    float lv = __shfl(lsum, row);
    rl[r] = 1.0f / lv;
  }
#pragma unroll
  for (int r = 0; r < 16; r++) {
    int row = (r & 3) + 8 * (r >> 2) + 4 * hi;
    size_t base = ((size_t)b * TT + q0 + w * 32 + row) * DM + (size_t)h * HD + ln;
#pragma unroll
    for (int dsub = 0; dsub < 4; dsub++)
      Oa[base + dsub * 32] = (f16)(o[dsub][r] * rl[r]);
  }
}

extern "C" void kernel_launch(void* const* d_in, const int* in_sizes, int n_in,
                              void* d_out, int out_size, void* d_ws, size_t ws_size,
                              hipStream_t stream) {
  const float* hidden = (const float*)d_in[0];
  const int* pos = (const int*)d_in[1];
  const float* Wq = (const float*)d_in[2];
  const float* Wk = (const float*)d_in[3];
  const float* Wv = (const float*)d_in[4];
  const float* Wo = (const float*)d_in[5];
  const float* qw = (const float*)d_in[6];
  const float* kw = (const float*)d_in[7];
  float* out = (float*)d_out;

  char* p = (char*)d_ws;
  auto take = [&](size_t n) {
    void* r = (void*)p;
    p += (n + 255) & ~(size_t)255;
    return r;
  };
  f16* Xb = (f16*)take((size_t)4096 * 2048 * 2);
  f16* WqkvT = (f16*)take((size_t)3072 * 2048 * 2);
  f16* WoT = (f16*)take((size_t)2048 * 2048 * 2);
  f16* QKVb = (f16*)take((size_t)4096 * 3072 * 2);
  f16* Qr = (f16*)take((size_t)BB * HQ * TT * HD * 2);
  f16* Kr = (f16*)take((size_t)BB * HKV * TT * HD * 2);
  f16* Vt = (f16*)take((size_t)BB * HKV * TT * HD * 2);
  f16* Attn = (f16*)take((size_t)4096 * 2048 * 2);

  k_prep<<<14336, 256, 0, stream>>>(hidden, Wq, Wk, Wv, Wo, Xb, WqkvT, WoT);
  k_gemm8<192, 3072, true><<<256, 512, 0, stream>>>(Xb, WqkvT, QKVb, 4096, 2048);
  k_post<<<6144, 256, 0, stream>>>(QKVb, pos, qw, kw, Qr, Kr, Vt);
  k_attn2<<<dim3(16, 16, 2), 256, 0, stream>>>(Qr, Kr, Vt, Attn);
  k_gemm8<128, 2048, false><<<256, 512, 0, stream>>>(Attn, WoT, out, 4096, 2048);
}

// Round 17
// 189.878 us; speedup vs baseline: 1.0431x; 1.0069x over previous
//
#include <hip/hip_runtime.h>
#include <cstdint>
#include <cstddef>

#define DM 2048
#define TT 2048
#define BB 2
#define HQ 16
#define HKV 4
#define HD 128

typedef _Float16 f16;
using f16x8 = __attribute__((ext_vector_type(8))) f16;
using f32x4 = __attribute__((ext_vector_type(4))) float;
using f32x16 = __attribute__((ext_vector_type(16))) float;
using u32x4 = __attribute__((ext_vector_type(4))) uint32_t;

#define MFMA16(a, b, c) __builtin_amdgcn_mfma_f32_16x16x32_f16(a, b, c, 0, 0, 0)
#define MFMA32(a, b, c) __builtin_amdgcn_mfma_f32_32x32x16_f16(a, b, c, 0, 0, 0)

typedef __attribute__((address_space(1))) const void gvoid_t;
typedef __attribute__((address_space(3))) void lvoid_t;
static __device__ __forceinline__ void gload16(const void* g, void* l) {
  __builtin_amdgcn_global_load_lds((gvoid_t*)g, (lvoid_t*)l, 16, 0, 0);
}

static __device__ __forceinline__ float fast_exp2(float x) {
#if __has_builtin(__builtin_amdgcn_exp2f)
  return __builtin_amdgcn_exp2f(x);
#else
  return exp2f(x);
#endif
}

static __device__ __forceinline__ uint32_t cvt_pk_u32(float a, float b) {
  auto h2 = __builtin_amdgcn_cvt_pkrtz(a, b);
  return __builtin_bit_cast(uint32_t, h2);
}

// ---- prep: fp32->f16 convert of hidden  +  all weight transposes, one launch ----
__global__ __launch_bounds__(256) void k_prep(const float* __restrict__ hidden,
                                              const float* __restrict__ Wq,
                                              const float* __restrict__ Wk,
                                              const float* __restrict__ Wv,
                                              const float* __restrict__ Wo,
                                              f16* __restrict__ Xb,
                                              f16* __restrict__ WqkvT,
                                              f16* __restrict__ WoT) {
  int t = blockIdx.x;
  int tid = threadIdx.x;
  if (t < 4096) {  // convert: 8 floats per thread
    int i = t * 256 + tid;
    const float4* pin = (const float4*)hidden;
    float4 a = pin[2 * i], b = pin[2 * i + 1];
    f16x8 o = {(f16)a.x, (f16)a.y, (f16)a.z, (f16)a.w,
               (f16)b.x, (f16)b.y, (f16)b.z, (f16)b.w};
    *(f16x8*)&Xb[(size_t)8 * i] = o;
    return;
  }
  __shared__ float tile[32][33];
  t -= 4096;
  const float* in;
  f16* out;
  int N, nx;
  if (t < 4096) {
    in = Wq; out = WqkvT; N = 2048; nx = 64;
  } else if (t < 5120) {
    t -= 4096; in = Wk; out = WqkvT + (size_t)2048 * 2048; N = 512; nx = 16;
  } else if (t < 6144) {
    t -= 5120; in = Wv; out = WqkvT + (size_t)2560 * 2048; N = 512; nx = 16;
  } else {
    t -= 6144; in = Wo; out = WoT; N = 2048; nx = 64;
  }
  int n0 = (t % nx) * 32, k0 = (t / nx) * 32;
  int tx = tid & 31, ty = tid >> 5;
#pragma unroll
  for (int r = 0; r < 32; r += 8) tile[ty + r][tx] = in[(size_t)(k0 + ty + r) * N + n0 + tx];
  __syncthreads();
#pragma unroll
  for (int r = 0; r < 32; r += 8)
    out[(size_t)(n0 + ty + r) * 2048 + k0 + tx] = (f16)tile[tx][ty + r];
}

// ---- 8-wave 256xBN MFMA GEMM, barrier-light: 1 vmcnt(0)+barrier per K-tile ----
// C[M,N] = A[M,K] * BT[N,K]^T. 512 threads = 8 waves (2M x 4N), 128 x BN/4 out/wave.
template <int BN_, int N_, bool OUT_F16>
__global__ __launch_bounds__(512, 2) void k_gemm8(const f16* __restrict__ A,
                                                  const f16* __restrict__ BT,
                                                  void* __restrict__ Cp, int M, int K) {
  constexpr int NF = BN_ / 64;   // 16-col B-fragments per wave
  constexpr int BI = BN_ / 64;   // B staging issues (64 rows each)
  __shared__ alignas(16) char Abuf[2][256 * 128];  // 256 rows x 128B, linear
  __shared__ alignas(16) char Bbuf[2][BN_ * 128];
  constexpr int NT = N_ / BN_;
  // T1: XCD-aware bijective remap (grid % 8 == 0)
  int bid0 = blockIdx.x;
  int bid = (bid0 & 7) * (gridDim.x >> 3) + (bid0 >> 3);
  int m0 = (bid / NT) * 256, n0 = (bid % NT) * BN_;
  int tid = threadIdx.x;
  int lane = tid & 63, w = tid >> 6;
  int wr = w >> 2, wc = w & 3;
  int g = lane >> 4, c = lane & 15;
  int rswz = (c & 7) << 4;  // read-side XOR (fragment row&7 == c&7)

  // staging: issue i covers rows 64i..64i+63; source pre-swizzled so that
  // linear LDS[row][cb] == global[row][cb ^ ((row&7)<<4)]
  int srow = tid >> 3;                     // 0..63 within issue
  int scbs = ((tid & 7) * 16) ^ ((srow & 7) << 4);
  const char* Ag = (const char*)A + (size_t)(m0 + srow) * (K * 2) + scbs;
  const char* Bg = (const char*)BT + (size_t)(n0 + srow) * (K * 2) + scbs;
  int lbase = w * 1024;  // wave-uniform LDS base; HW adds lane*16

  f32x4 acc[8][NF] = {};
  int nk = K >> 6;

  auto stageA = [&](int buf, int kt, int i) {
    gload16(Ag + (size_t)(i * 64) * (K * 2) + (size_t)kt * 128,
            &Abuf[buf][i * 8192 + lbase]);
  };
  auto stageB = [&](int buf, int kt, int i) {
    gload16(Bg + (size_t)(i * 64) * (K * 2) + (size_t)kt * 128,
            &Bbuf[buf][i * 8192 + lbase]);
  };

  // prologue: stage K-tile 0 into buf 0, drain, publish
  {
#pragma unroll
    for (int i = 0; i < 4; i++) stageA(0, 0, i);
#pragma unroll
    for (int i = 0; i < BI; i++) stageB(0, 0, i);
    asm volatile("s_waitcnt vmcnt(0)" ::: "memory");
    __builtin_amdgcn_s_barrier();
  }

  for (int kt = 0; kt < nk; kt++) {
    int cur = kt & 1, nxt = cur ^ 1;
    bool more = (kt + 1) < nk;
    const char* Ab = Abuf[cur];
    const char* Bb = Bbuf[cur];
    f16x8 bf[NF][2], af[2][2];
#pragma unroll
    for (int p = 0; p < 4; p++) {
      if (p == 0) {
#pragma unroll
        for (int nn = 0; nn < NF; nn++)
#pragma unroll
          for (int kk = 0; kk < 2; kk++) {
            int R = wc * (NF * 16) + nn * 16 + c;
            bf[nn][kk] = *(const f16x8*)(Bb + R * 128 + ((kk * 64 + g * 16) ^ rswz));
          }
      }
#pragma unroll
      for (int j = 0; j < 2; j++)
#pragma unroll
        for (int kk = 0; kk < 2; kk++) {
          int R = wr * 128 + (p * 2 + j) * 16 + c;
          af[j][kk] = *(const f16x8*)(Ab + R * 128 + ((kk * 64 + g * 16) ^ rswz));
        }
      // issue-early: all next-tile loads go out in phases 0-1 (max slack to drain)
      if (more) {
        if (p == 0) {
          stageA(nxt, kt + 1, 0); stageA(nxt, kt + 1, 1); stageB(nxt, kt + 1, 0);
        } else if (p == 1) {
          stageA(nxt, kt + 1, 2); stageA(nxt, kt + 1, 3); stageB(nxt, kt + 1, 1);
          if constexpr (BI == 3) stageB(nxt, kt + 1, 2);
        }
      }
      __builtin_amdgcn_s_barrier();  // pre-MFMA lockstep (no post-MFMA barrier:
                                     // phase p+1 ds_reads overlap phase p MFMA)
      __builtin_amdgcn_s_setprio(1);
#pragma unroll
      for (int j = 0; j < 2; j++)
#pragma unroll
        for (int nn = 0; nn < NF; nn++)
#pragma unroll
          for (int kk = 0; kk < 2; kk++)
            acc[p * 2 + j][nn] = MFMA16(af[j][kk], bf[nn][kk], acc[p * 2 + j][nn]);
      __builtin_amdgcn_s_setprio(0);
    }
    // K-tile boundary: the only full drain — next tile's LDS image must be
    // complete (vmcnt) and all waves done reading buf[cur] (barrier).
    asm volatile("s_waitcnt vmcnt(0)" ::: "memory");
    __builtin_amdgcn_s_barrier();
  }
  // epilogue: C-write
#pragma unroll
  for (int mm = 0; mm < 8; mm++)
#pragma unroll
    for (int nn = 0; nn < NF; nn++)
#pragma unroll
      for (int r = 0; r < 4; r++) {
        size_t row = m0 + wr * 128 + mm * 16 + g * 4 + r;
        size_t col = n0 + wc * (NF * 16) + nn * 16 + c;
        float v = acc[mm][nn][r];
        if constexpr (OUT_F16)
          ((f16*)Cp)[row * N_ + col] = (f16)v;
        else
          ((float*)Cp)[row * N_ + col] = v;
      }
}

// ---- post-QKV: RMSNorm+RoPE (Q,K) and V transpose, one launch ----
__global__ __launch_bounds__(256) void k_post(const f16* __restrict__ qkv,
                                              const int* __restrict__ pos_ids,
                                              const float* __restrict__ qw,
                                              const float* __restrict__ kw,
                                              f16* __restrict__ Qo, f16* __restrict__ Ko,
                                              f16* __restrict__ Vt) {
  int blk = blockIdx.x;
  int tid = threadIdx.x;
  if (blk < 4096) {  // norm+rope
    int bt = blk;
    int b = bt >> 11, t = bt & 2047;
    int w = tid >> 6, lane = tid & 63;
    const f16* row = qkv + (size_t)bt * 3072;
    float pq = (float)pos_ids[t];
    float pk = (float)t;
    float inv = expf(-(float)lane * 0.14391156831212787f);
    float aq = pq * inv, ak = pk * inv;
    float snq = sinf(aq), csq = cosf(aq);
    float snk = sinf(ak), csk = cosf(ak);
    for (int hi = w; hi < 20; hi += 4) {
      bool isq = hi < 16;
      int off = isq ? hi * 128 : 2048 + (hi - 16) * 128;
      float x1 = (float)row[off + 2 * lane];
      float x2 = (float)row[off + 2 * lane + 1];
      float ss = x1 * x1 + x2 * x2;
#pragma unroll
      for (int o = 1; o < 64; o <<= 1) ss += __shfl_xor(ss, o);
      float rms = rsqrtf(ss * (1.0f / 128.0f) + 1e-6f);
      const float* wt = isq ? qw : kw;
      float n1 = x1 * rms * wt[2 * lane], n2 = x2 * rms * wt[2 * lane + 1];
      float sn = isq ? snq : snk, cs = isq ? csq : csk;
      f16 r1 = (f16)(n1 * cs - n2 * sn), r2 = (f16)(n1 * sn + n2 * cs);
      if (isq) {
        f16* dst = Qo + (((size_t)b * HQ + hi) * TT + t) * HD;
        dst[2 * lane] = r1;
        dst[2 * lane + 1] = r2;
      } else {
        f16* dst = Ko + (((size_t)b * HKV + (hi - 16)) * TT + t) * HD;
        dst[2 * lane] = r1;
        dst[2 * lane + 1] = r2;
      }
    }
    return;
  }
  // V transpose: Vt[b][hkv][d][t]
  __shared__ f16 tile[32][34];
  int t2 = blk - 4096;
  int t0 = (t2 & 63) * 32, d0 = ((t2 >> 6) & 3) * 32;
  int bh = t2 >> 8;
  int b = bh >> 2, hkv = bh & 3;
  int tx = tid & 31, ty = tid >> 5;
  const f16* src = qkv + (size_t)b * 2048 * 3072 + 2560 + hkv * 128;
#pragma unroll
  for (int r = 0; r < 32; r += 8)
    tile[ty + r][tx] = src[(size_t)(t0 + ty + r) * 3072 + d0 + tx];
  __syncthreads();
  f16* dst = Vt + ((size_t)bh * HD + d0) * TT + t0;
#pragma unroll
  for (int r = 0; r < 32; r += 8)
    dst[(size_t)(ty + r) * TT + tx] = tile[tx][ty + r];
}

// ---- attention: 4 waves x 32q, 64-key tiles, swapped QK^T, gload_lds dbuf staging ----
__global__ __launch_bounds__(256, 2) void k_attn2(const f16* __restrict__ Q,
                                                  const f16* __restrict__ Kc,
                                                  const f16* __restrict__ Vt,
                                                  f16* __restrict__ Oa) {
  __shared__ alignas(16) char KsC[2][64 * 256];   // K: 64 keys x 128 d (256B rows)
  __shared__ alignas(16) char VsC[2][128 * 128];  // V^T: 128 d x 64 keys (128B rows)
  int qt = blockIdx.x, h = blockIdx.y, b = blockIdx.z;
  // balance remap (r11, measured best): blocks i and i+256 share a CU and differ
  // only in b -> pair (qt, 15-qt)
  qt = b ? (15 - qt) : qt;
  int q0 = qt * 128, hkv = h >> 2;
  int tid = threadIdx.x;
  int w = tid >> 6, lane = tid & 63, ln = lane & 31, hi = lane >> 5;
  const char* KbB = (const char*)(Kc + ((size_t)b * HKV + hkv) * TT * HD);
  const char* VbB = (const char*)(Vt + ((size_t)b * HKV + hkv) * (size_t)HD * TT);
  int q = q0 + w * 32 + ln;
  const f16* Qp = Q + (((size_t)b * HQ + h) * TT + q) * HD + hi * 8;
  f16x8 qf[8];
#pragma unroll
  for (int st = 0; st < 8; st++) qf[st] = *(const f16x8*)&Qp[st * 16];
  f32x16 o[4] = {};
  float lsum = 0.f;
  int kfswz = (ln & 7) << 4;

  int krow0 = w * 4 + (lane >> 4);
  int kswzb = ((lane & 15) * 16) ^ ((krow0 & 7) << 4);
  int vrow0 = w * 8 + (lane >> 3);
  int vswzb = ((lane & 7) * 16) ^ ((vrow0 & 7) << 4);

  int k0max = (q0 + 127) & ~63;
  int wlo = (q0 - 1023 > 128) ? ((q0 - 1023) & ~63) : 128;
  int nw = (k0max >= wlo) ? ((k0max - wlo) >> 6) + 1 : 0;
  int ntiles = 2 + nw;
  int qw = q0 + w * 32;

  const float C1 = 0.12751791217100872f;  // (1/sqrt(128)) * log2(e)
  const float C2 = 5.7707801635534255f;   // 4.0 * log2(e)  (fixed softmax shift)

  auto stage = [&](int buf, int k0) {
    const char* ks = KbB + (size_t)(k0 + krow0) * 256 + kswzb;
    const char* vs = VbB + (size_t)vrow0 * (TT * 2) + (size_t)k0 * 2 + vswzb;
    char* kd = KsC[buf] + w * 1024;
    char* vd = VsC[buf] + w * 1024;
#pragma unroll
    for (int j = 0; j < 4; j++) gload16(ks + (size_t)j * 4096, kd + j * 4096);
#pragma unroll
    for (int j = 0; j < 4; j++) gload16(vs + (size_t)j * 32 * (TT * 2), vd + j * 4096);
  };

  stage(0, 0);
  __syncthreads();
  int cur = 0;

  for (int ti = 0; ti < ntiles; ti++) {
    int k0 = (ti < 2) ? ti * 64 : wlo + (ti - 2) * 64;
    bool havenext = (ti + 1 < ntiles);
    if (havenext) {
      int k0n = (ti + 1 < 2) ? 64 : wlo + (ti - 1) * 64;
      stage(cur ^ 1, k0n);
    }
    bool needmask = false;
    if (ti >= 2) {
      int wsmax = qw + 31 - 1023;
      if (wsmax < 128) wsmax = 128;
      needmask = !((k0 + 63 <= qw) && (k0 >= wsmax));
    }
    f16x8 pa[2][2];
#pragma unroll
    for (int ksub = 0; ksub < 2; ksub++) {
      f32x16 s0 = {}, s1 = {};
      const char* krow = KsC[cur] + (ksub * 32 + ln) * 256;
      __builtin_amdgcn_s_setprio(1);
#pragma unroll
      for (int st = 0; st < 8; st += 2) {
        f16x8 kf0 = *(const f16x8*)(krow + ((st * 32 + hi * 16) ^ kfswz));
        f16x8 kf1 = *(const f16x8*)(krow + (((st + 1) * 32 + hi * 16) ^ kfswz));
        s0 = MFMA32(kf0, qf[st], s0);
        s1 = MFMA32(kf1, qf[st + 1], s1);
      }
      __builtin_amdgcn_s_setprio(0);
      f32x16 s = s0 + s1;
      int qmk = q - (k0 + ksub * 32 + 4 * hi);
      float pr[16];
#pragma unroll
      for (int r = 0; r < 16; r++) {
        float e = fast_exp2(s[r] * C1 - C2);
        if (needmask) {
          int kk = (r & 3) + 8 * (r >> 2);
          e = ((uint32_t)(qmk - kk) < 1024u) ? e : 0.0f;
        }
        lsum += e;
        pr[r] = e;
      }
      uint32_t c[8];
#pragma unroll
      for (int i = 0; i < 8; i++) c[i] = cvt_pk_u32(pr[2 * i], pr[2 * i + 1]);
      {
        uint32_t x0 = __shfl_xor(c[0], 32), x1 = __shfl_xor(c[1], 32);
        uint32_t x2 = __shfl_xor(c[2], 32), x3 = __shfl_xor(c[3], 32);
        u32x4 t0 = {hi ? x2 : c[0], hi ? x3 : c[1], hi ? c[2] : x0, hi ? c[3] : x1};
        pa[ksub][0] = __builtin_bit_cast(f16x8, t0);
        uint32_t x4 = __shfl_xor(c[4], 32), x5 = __shfl_xor(c[5], 32);
        uint32_t x6 = __shfl_xor(c[6], 32), x7 = __shfl_xor(c[7], 32);
        u32x4 t1 = {hi ? x6 : c[4], hi ? x7 : c[5], hi ? c[6] : x4, hi ? c[7] : x5};
        pa[ksub][1] = __builtin_bit_cast(f16x8, t1);
      }
    }
    __builtin_amdgcn_s_setprio(1);
#pragma unroll
    for (int dsub = 0; dsub < 4; dsub++) {
      const char* vrow = VsC[cur] + (dsub * 32 + ln) * 128;
#pragma unroll
      for (int ksub = 0; ksub < 2; ksub++)
#pragma unroll
        for (int st2 = 0; st2 < 2; st2++) {
          f16x8 vf = *(const f16x8*)(vrow + ((ksub * 64 + st2 * 32 + hi * 16) ^ kfswz));
          o[dsub] = MFMA32(pa[ksub][st2], vf, o[dsub]);
        }
    }
    __builtin_amdgcn_s_setprio(0);
    __syncthreads();
    cur ^= 1;
  }
  // epilogue: finish l, scale, store
  lsum += __shfl_xor(lsum, 32);
  float rl[16];
#pragma unroll
  for (int r = 0; r < 16; r++) {
    int row = (r & 3) + 8 * (r >> 2) + 4 * hi;
    float lv = __shfl(lsum, row);
    rl[r] = 1.0f / lv;
  }
#pragma unroll
  for (int r = 0; r < 16; r++) {
    int row = (r & 3) + 8 * (r >> 2) + 4 * hi;
    size_t base = ((size_t)b * TT + q0 + w * 32 + row) * DM + (size_t)h * HD + ln;
#pragma unroll
    for (int dsub = 0; dsub < 4; dsub++)
      Oa[base + dsub * 32] = (f16)(o[dsub][r] * rl[r]);
  }
}

extern "C" void kernel_launch(void* const* d_in, const int* in_sizes, int n_in,
                              void* d_out, int out_size, void* d_ws, size_t ws_size,
                              hipStream_t stream) {
  const float* hidden = (const float*)d_in[0];
  const int* pos = (const int*)d_in[1];
  const float* Wq = (const float*)d_in[2];
  const float* Wk = (const float*)d_in[3];
  const float* Wv = (const float*)d_in[4];
  const float* Wo = (const float*)d_in[5];
  const float* qw = (const float*)d_in[6];
  const float* kw = (const float*)d_in[7];
  float* out = (float*)d_out;

  char* p = (char*)d_ws;
  auto take = [&](size_t n) {
    void* r = (void*)p;
    p += (n + 255) & ~(size_t)255;
    return r;
  };
  f16* Xb = (f16*)take((size_t)4096 * 2048 * 2);
  f16* WqkvT = (f16*)take((size_t)3072 * 2048 * 2);
  f16* WoT = (f16*)take((size_t)2048 * 2048 * 2);
  f16* QKVb = (f16*)take((size_t)4096 * 3072 * 2);
  f16* Qr = (f16*)take((size_t)BB * HQ * TT * HD * 2);
  f16* Kr = (f16*)take((size_t)BB * HKV * TT * HD * 2);
  f16* Vt = (f16*)take((size_t)BB * HKV * TT * HD * 2);
  f16* Attn = (f16*)take((size_t)4096 * 2048 * 2);

  k_prep<<<14336, 256, 0, stream>>>(hidden, Wq, Wk, Wv, Wo, Xb, WqkvT, WoT);
  k_gemm8<192, 3072, true><<<256, 512, 0, stream>>>(Xb, WqkvT, QKVb, 4096, 2048);
  k_post<<<6144, 256, 0, stream>>>(QKVb, pos, qw, kw, Qr, Kr, Vt);
  k_attn2<<<dim3(16, 16, 2), 256, 0, stream>>>(Qr, Kr, Vt, Attn);
  k_gemm8<128, 2048, false><<<256, 512, 0, stream>>>(Attn, WoT, out, 4096, 2048);
}

// Round 18
// 189.453 us; speedup vs baseline: 1.0454x; 1.0022x over previous
//
#include <hip/hip_runtime.h>
#include <cstdint>
#include <cstddef>

#define DM 2048
#define TT 2048
#define BB 2
#define HQ 16
#define HKV 4
#define HD 128

typedef _Float16 f16;
using f16x8 = __attribute__((ext_vector_type(8))) f16;
using f16x2v = __attribute__((ext_vector_type(2))) f16;
using f32x4 = __attribute__((ext_vector_type(4))) float;
using f32x16 = __attribute__((ext_vector_type(16))) float;
using u32x4 = __attribute__((ext_vector_type(4))) uint32_t;

#define MFMA16(a, b, c) __builtin_amdgcn_mfma_f32_16x16x32_f16(a, b, c, 0, 0, 0)
#define MFMA32(a, b, c) __builtin_amdgcn_mfma_f32_32x32x16_f16(a, b, c, 0, 0, 0)

typedef __attribute__((address_space(1))) const void gvoid_t;
typedef __attribute__((address_space(3))) void lvoid_t;
static __device__ __forceinline__ void gload16(const void* g, void* l) {
  __builtin_amdgcn_global_load_lds((gvoid_t*)g, (lvoid_t*)l, 16, 0, 0);
}

static __device__ __forceinline__ float fast_exp2(float x) {
#if __has_builtin(__builtin_amdgcn_exp2f)
  return __builtin_amdgcn_exp2f(x);
#else
  return exp2f(x);
#endif
}

static __device__ __forceinline__ uint32_t cvt_pk_u32(float a, float b) {
  auto h2 = __builtin_amdgcn_cvt_pkrtz(a, b);
  return __builtin_bit_cast(uint32_t, h2);
}

// ---- prep: fp32->f16 convert of hidden  +  all weight transposes, one launch ----
__global__ __launch_bounds__(256) void k_prep(const float* __restrict__ hidden,
                                              const float* __restrict__ Wq,
                                              const float* __restrict__ Wk,
                                              const float* __restrict__ Wv,
                                              const float* __restrict__ Wo,
                                              f16* __restrict__ Xb,
                                              f16* __restrict__ WqkvT,
                                              f16* __restrict__ WoT) {
  int t = blockIdx.x;
  int tid = threadIdx.x;
  if (t < 4096) {  // convert: 8 floats per thread
    int i = t * 256 + tid;
    const float4* pin = (const float4*)hidden;
    float4 a = pin[2 * i], b = pin[2 * i + 1];
    f16x8 o = {(f16)a.x, (f16)a.y, (f16)a.z, (f16)a.w,
               (f16)b.x, (f16)b.y, (f16)b.z, (f16)b.w};
    *(f16x8*)&Xb[(size_t)8 * i] = o;
    return;
  }
  __shared__ float tile[32][33];
  t -= 4096;
  const float* in;
  f16* out;
  int N, nx;
  if (t < 4096) {
    in = Wq; out = WqkvT; N = 2048; nx = 64;
  } else if (t < 5120) {
    t -= 4096; in = Wk; out = WqkvT + (size_t)2048 * 2048; N = 512; nx = 16;
  } else if (t < 6144) {
    t -= 5120; in = Wv; out = WqkvT + (size_t)2560 * 2048; N = 512; nx = 16;
  } else {
    t -= 6144; in = Wo; out = WoT; N = 2048; nx = 64;
  }
  int n0 = (t % nx) * 32, k0 = (t / nx) * 32;
  int tx = tid & 31, ty = tid >> 5;
#pragma unroll
  for (int r = 0; r < 32; r += 8) tile[ty + r][tx] = in[(size_t)(k0 + ty + r) * N + n0 + tx];
  __syncthreads();
#pragma unroll
  for (int r = 0; r < 32; r += 8)
    out[(size_t)(n0 + ty + r) * 2048 + k0 + tx] = (f16)tile[tx][ty + r];
}

// ---- 8-wave 256xBN MFMA GEMM, barrier-light: 1 vmcnt(0)+barrier per K-tile ----
// C[M,N] = A[M,K] * BT[N,K]^T. 512 threads = 8 waves (2M x 4N), 128 x BN/4 out/wave.
template <int BN_, int N_, bool OUT_F16>
__global__ __launch_bounds__(512, 2) void k_gemm8(const f16* __restrict__ A,
                                                  const f16* __restrict__ BT,
                                                  void* __restrict__ Cp, int M, int K) {
  constexpr int NF = BN_ / 64;   // 16-col B-fragments per wave
  constexpr int BI = BN_ / 64;   // B staging issues (64 rows each)
  __shared__ alignas(16) char Abuf[2][256 * 128];  // 256 rows x 128B, linear
  __shared__ alignas(16) char Bbuf[2][BN_ * 128];
  constexpr int NT = N_ / BN_;
  // T1: XCD-aware bijective remap (grid % 8 == 0)
  int bid0 = blockIdx.x;
  int bid = (bid0 & 7) * (gridDim.x >> 3) + (bid0 >> 3);
  int m0 = (bid / NT) * 256, n0 = (bid % NT) * BN_;
  int tid = threadIdx.x;
  int lane = tid & 63, w = tid >> 6;
  int wr = w >> 2, wc = w & 3;
  int g = lane >> 4, c = lane & 15;
  int rswz = (c & 7) << 4;  // read-side XOR (fragment row&7 == c&7)

  // staging: issue i covers rows 64i..64i+63; source pre-swizzled so that
  // linear LDS[row][cb] == global[row][cb ^ ((row&7)<<4)]
  int srow = tid >> 3;                     // 0..63 within issue
  int scbs = ((tid & 7) * 16) ^ ((srow & 7) << 4);
  const char* Ag = (const char*)A + (size_t)(m0 + srow) * (K * 2) + scbs;
  const char* Bg = (const char*)BT + (size_t)(n0 + srow) * (K * 2) + scbs;
  int lbase = w * 1024;  // wave-uniform LDS base; HW adds lane*16

  f32x4 acc[8][NF] = {};
  int nk = K >> 6;

  auto stageA = [&](int buf, int kt, int i) {
    gload16(Ag + (size_t)(i * 64) * (K * 2) + (size_t)kt * 128,
            &Abuf[buf][i * 8192 + lbase]);
  };
  auto stageB = [&](int buf, int kt, int i) {
    gload16(Bg + (size_t)(i * 64) * (K * 2) + (size_t)kt * 128,
            &Bbuf[buf][i * 8192 + lbase]);
  };

  // prologue: stage K-tile 0 into buf 0, drain, publish
  {
#pragma unroll
    for (int i = 0; i < 4; i++) stageA(0, 0, i);
#pragma unroll
    for (int i = 0; i < BI; i++) stageB(0, 0, i);
    asm volatile("s_waitcnt vmcnt(0)" ::: "memory");
    __builtin_amdgcn_s_barrier();
  }

  for (int kt = 0; kt < nk; kt++) {
    int cur = kt & 1, nxt = cur ^ 1;
    bool more = (kt + 1) < nk;
    const char* Ab = Abuf[cur];
    const char* Bb = Bbuf[cur];
    f16x8 bf[NF][2], af[2][2];
#pragma unroll
    for (int p = 0; p < 4; p++) {
      if (p == 0) {
#pragma unroll
        for (int nn = 0; nn < NF; nn++)
#pragma unroll
          for (int kk = 0; kk < 2; kk++) {
            int R = wc * (NF * 16) + nn * 16 + c;
            bf[nn][kk] = *(const f16x8*)(Bb + R * 128 + ((kk * 64 + g * 16) ^ rswz));
          }
      }
#pragma unroll
      for (int j = 0; j < 2; j++)
#pragma unroll
        for (int kk = 0; kk < 2; kk++) {
          int R = wr * 128 + (p * 2 + j) * 16 + c;
          af[j][kk] = *(const f16x8*)(Ab + R * 128 + ((kk * 64 + g * 16) ^ rswz));
        }
      // issue-early: all next-tile loads go out in phases 0-1 (max slack to drain)
      if (more) {
        if (p == 0) {
          stageA(nxt, kt + 1, 0); stageA(nxt, kt + 1, 1); stageB(nxt, kt + 1, 0);
        } else if (p == 1) {
          stageA(nxt, kt + 1, 2); stageA(nxt, kt + 1, 3); stageB(nxt, kt + 1, 1);
          if constexpr (BI == 3) stageB(nxt, kt + 1, 2);
        }
      }
      __builtin_amdgcn_s_barrier();  // pre-MFMA lockstep (no post-MFMA barrier:
                                     // phase p+1 ds_reads overlap phase p MFMA)
      __builtin_amdgcn_s_setprio(1);
#pragma unroll
      for (int j = 0; j < 2; j++)
#pragma unroll
        for (int nn = 0; nn < NF; nn++)
#pragma unroll
          for (int kk = 0; kk < 2; kk++)
            acc[p * 2 + j][nn] = MFMA16(af[j][kk], bf[nn][kk], acc[p * 2 + j][nn]);
      __builtin_amdgcn_s_setprio(0);
    }
    // K-tile boundary: the only full drain — next tile's LDS image must be
    // complete (vmcnt) and all waves done reading buf[cur] (barrier).
    asm volatile("s_waitcnt vmcnt(0)" ::: "memory");
    __builtin_amdgcn_s_barrier();
  }
  // epilogue: C-write
#pragma unroll
  for (int mm = 0; mm < 8; mm++)
#pragma unroll
    for (int nn = 0; nn < NF; nn++)
#pragma unroll
      for (int r = 0; r < 4; r++) {
        size_t row = m0 + wr * 128 + mm * 16 + g * 4 + r;
        size_t col = n0 + wc * (NF * 16) + nn * 16 + c;
        float v = acc[mm][nn][r];
        if constexpr (OUT_F16)
          ((f16*)Cp)[row * N_ + col] = (f16)v;
        else
          ((float*)Cp)[row * N_ + col] = v;
      }
}

// ---- post-QKV: RMSNorm+RoPE (Q,K) and V transpose, one launch ----
__global__ __launch_bounds__(256) void k_post(const f16* __restrict__ qkv,
                                              const int* __restrict__ pos_ids,
                                              const float* __restrict__ qw,
                                              const float* __restrict__ kw,
                                              f16* __restrict__ Qo, f16* __restrict__ Ko,
                                              f16* __restrict__ Vt) {
  int blk = blockIdx.x;
  int tid = threadIdx.x;
  if (blk < 4096) {  // norm+rope, vectorized 4B loads/stores (G13)
    int bt = blk;
    int b = bt >> 11, t = bt & 2047;
    int w = tid >> 6, lane = tid & 63;
    const f16* row = qkv + (size_t)bt * 3072;
    float pq = (float)pos_ids[t];
    float pk = (float)t;
    float inv = expf(-(float)lane * 0.14391156831212787f);
    float aq = pq * inv, ak = pk * inv;
    float snq = sinf(aq), csq = cosf(aq);
    float snk = sinf(ak), csk = cosf(ak);
    for (int hi = w; hi < 20; hi += 4) {
      bool isq = hi < 16;
      int off = isq ? hi * 128 : 2048 + (hi - 16) * 128;
      f16x2v xv = *(const f16x2v*)&row[off + 2 * lane];
      float x1 = (float)xv[0];
      float x2 = (float)xv[1];
      float ss = x1 * x1 + x2 * x2;
#pragma unroll
      for (int o = 1; o < 64; o <<= 1) ss += __shfl_xor(ss, o);
      float rms = rsqrtf(ss * (1.0f / 128.0f) + 1e-6f);
      const float* wt = isq ? qw : kw;
      float2 wv = *(const float2*)&wt[2 * lane];
      float n1 = x1 * rms * wv.x, n2 = x2 * rms * wv.y;
      float sn = isq ? snq : snk, cs = isq ? csq : csk;
      f16x2v rv = {(f16)(n1 * cs - n2 * sn), (f16)(n1 * sn + n2 * cs)};
      if (isq) {
        f16* dst = Qo + (((size_t)b * HQ + hi) * TT + t) * HD;
        *(f16x2v*)&dst[2 * lane] = rv;
      } else {
        f16* dst = Ko + (((size_t)b * HKV + (hi - 16)) * TT + t) * HD;
        *(f16x2v*)&dst[2 * lane] = rv;
      }
    }
    return;
  }
  // V transpose: Vt[b][hkv][d][t]
  __shared__ f16 tile[32][34];
  int t2 = blk - 4096;
  int t0 = (t2 & 63) * 32, d0 = ((t2 >> 6) & 3) * 32;
  int bh = t2 >> 8;
  int b = bh >> 2, hkv = bh & 3;
  int tx = tid & 31, ty = tid >> 5;
  const f16* src = qkv + (size_t)b * 2048 * 3072 + 2560 + hkv * 128;
#pragma unroll
  for (int r = 0; r < 32; r += 8)
    tile[ty + r][tx] = src[(size_t)(t0 + ty + r) * 3072 + d0 + tx];
  __syncthreads();
  f16* dst = Vt + ((size_t)bh * HD + d0) * TT + t0;
#pragma unroll
  for (int r = 0; r < 32; r += 8)
    dst[(size_t)(ty + r) * TT + tx] = tile[tx][ty + r];
}

// ---- attention: 4 waves x 32q, 64-key tiles, swapped QK^T, gload_lds dbuf staging ----
__global__ __launch_bounds__(256, 2) void k_attn2(const f16* __restrict__ Q,
                                                  const f16* __restrict__ Kc,
                                                  const f16* __restrict__ Vt,
                                                  f16* __restrict__ Oa) {
  __shared__ alignas(16) char KsC[2][64 * 256];   // K: 64 keys x 128 d (256B rows)
  __shared__ alignas(16) char VsC[2][128 * 128];  // V^T: 128 d x 64 keys (128B rows)
  int qt = blockIdx.x, h = blockIdx.y, b = blockIdx.z;
  // balance remap (r11, measured best): blocks i and i+256 share a CU and differ
  // only in b -> pair (qt, 15-qt)
  qt = b ? (15 - qt) : qt;
  int q0 = qt * 128, hkv = h >> 2;
  int tid = threadIdx.x;
  int w = tid >> 6, lane = tid & 63, ln = lane & 31, hi = lane >> 5;
  const char* KbB = (const char*)(Kc + ((size_t)b * HKV + hkv) * TT * HD);
  const char* VbB = (const char*)(Vt + ((size_t)b * HKV + hkv) * (size_t)HD * TT);
  int q = q0 + w * 32 + ln;
  const f16* Qp = Q + (((size_t)b * HQ + h) * TT + q) * HD + hi * 8;
  f16x8 qf[8];
#pragma unroll
  for (int st = 0; st < 8; st++) qf[st] = *(const f16x8*)&Qp[st * 16];
  f32x16 o[4] = {};
  float lsum = 0.f;
  int kfswz = (ln & 7) << 4;

  int krow0 = w * 4 + (lane >> 4);
  int kswzb = ((lane & 15) * 16) ^ ((krow0 & 7) << 4);
  int vrow0 = w * 8 + (lane >> 3);
  int vswzb = ((lane & 7) * 16) ^ ((vrow0 & 7) << 4);

  int k0max = (q0 + 127) & ~63;
  int wlo = (q0 - 1023 > 128) ? ((q0 - 1023) & ~63) : 128;
  int nw = (k0max >= wlo) ? ((k0max - wlo) >> 6) + 1 : 0;
  int ntiles = 2 + nw;
  int qw = q0 + w * 32;

  const float C1 = 0.12751791217100872f;  // (1/sqrt(128)) * log2(e)
  const float C2 = 5.7707801635534255f;   // 4.0 * log2(e)  (fixed softmax shift)

  auto stage = [&](int buf, int k0) {
    const char* ks = KbB + (size_t)(k0 + krow0) * 256 + kswzb;
    const char* vs = VbB + (size_t)vrow0 * (TT * 2) + (size_t)k0 * 2 + vswzb;
    char* kd = KsC[buf] + w * 1024;
    char* vd = VsC[buf] + w * 1024;
#pragma unroll
    for (int j = 0; j < 4; j++) gload16(ks + (size_t)j * 4096, kd + j * 4096);
#pragma unroll
    for (int j = 0; j < 4; j++) gload16(vs + (size_t)j * 32 * (TT * 2), vd + j * 4096);
  };

  stage(0, 0);
  __syncthreads();
  int cur = 0;

  for (int ti = 0; ti < ntiles; ti++) {
    int k0 = (ti < 2) ? ti * 64 : wlo + (ti - 2) * 64;
    bool havenext = (ti + 1 < ntiles);
    if (havenext) {
      int k0n = (ti + 1 < 2) ? 64 : wlo + (ti - 1) * 64;
      stage(cur ^ 1, k0n);
    }
    bool needmask = false;
    if (ti >= 2) {
      int wsmax = qw + 31 - 1023;
      if (wsmax < 128) wsmax = 128;
      needmask = !((k0 + 63 <= qw) && (k0 >= wsmax));
    }
    f16x8 pa[2][2];
#pragma unroll
    for (int ksub = 0; ksub < 2; ksub++) {
      f32x16 s0 = {}, s1 = {};
      const char* krow = KsC[cur] + (ksub * 32 + ln) * 256;
      __builtin_amdgcn_s_setprio(1);
#pragma unroll
      for (int st = 0; st < 8; st += 2) {
        f16x8 kf0 = *(const f16x8*)(krow + ((st * 32 + hi * 16) ^ kfswz));
        f16x8 kf1 = *(const f16x8*)(krow + (((st + 1) * 32 + hi * 16) ^ kfswz));
        s0 = MFMA32(kf0, qf[st], s0);
        s1 = MFMA32(kf1, qf[st + 1], s1);
      }
      __builtin_amdgcn_s_setprio(0);
      f32x16 s = s0 + s1;
      int qmk = q - (k0 + ksub * 32 + 4 * hi);
      float pr[16];
#pragma unroll
      for (int r = 0; r < 16; r++) {
        float e = fast_exp2(s[r] * C1 - C2);
        if (needmask) {
          int kk = (r & 3) + 8 * (r >> 2);
          e = ((uint32_t)(qmk - kk) < 1024u) ? e : 0.0f;
        }
        lsum += e;
        pr[r] = e;
      }
      uint32_t c[8];
#pragma unroll
      for (int i = 0; i < 8; i++) c[i] = cvt_pk_u32(pr[2 * i], pr[2 * i + 1]);
      {
        uint32_t x0 = __shfl_xor(c[0], 32), x1 = __shfl_xor(c[1], 32);
        uint32_t x2 = __shfl_xor(c[2], 32), x3 = __shfl_xor(c[3], 32);
        u32x4 t0 = {hi ? x2 : c[0], hi ? x3 : c[1], hi ? c[2] : x0, hi ? c[3] : x1};
        pa[ksub][0] = __builtin_bit_cast(f16x8, t0);
        uint32_t x4 = __shfl_xor(c[4], 32), x5 = __shfl_xor(c[5], 32);
        uint32_t x6 = __shfl_xor(c[6], 32), x7 = __shfl_xor(c[7], 32);
        u32x4 t1 = {hi ? x6 : c[4], hi ? x7 : c[5], hi ? c[6] : x4, hi ? c[7] : x5};
        pa[ksub][1] = __builtin_bit_cast(f16x8, t1);
      }
    }
    __builtin_amdgcn_s_setprio(1);
#pragma unroll
    for (int dsub = 0; dsub < 4; dsub++) {
      const char* vrow = VsC[cur] + (dsub * 32 + ln) * 128;
#pragma unroll
      for (int ksub = 0; ksub < 2; ksub++)
#pragma unroll
        for (int st2 = 0; st2 < 2; st2++) {
          f16x8 vf = *(const f16x8*)(vrow + ((ksub * 64 + st2 * 32 + hi * 16) ^ kfswz));
          o[dsub] = MFMA32(pa[ksub][st2], vf, o[dsub]);
        }
    }
    __builtin_amdgcn_s_setprio(0);
    __syncthreads();
    cur ^= 1;
  }
  // epilogue: finish l, scale, store
  lsum += __shfl_xor(lsum, 32);
  float rl[16];
#pragma unroll
  for (int r = 0; r < 16; r++) {
    int row = (r & 3) + 8 * (r >> 2) + 4 * hi;
    float lv = __shfl(lsum, row);
    rl[r] = 1.0f / lv;
  }
#pragma unroll
  for (int r = 0; r < 16; r++) {
    int row = (r & 3) + 8 * (r >> 2) + 4 * hi;
    size_t base = ((size_t)b * TT + q0 + w * 32 + row) * DM + (size_t)h * HD + ln;
#pragma unroll
    for (int dsub = 0; dsub < 4; dsub++)
      Oa[base + dsub * 32] = (f16)(o[dsub][r] * rl[r]);
  }
}

extern "C" void kernel_launch(void* const* d_in, const int* in_sizes, int n_in,
                              void* d_out, int out_size, void* d_ws, size_t ws_size,
                              hipStream_t stream) {
  const float* hidden = (const float*)d_in[0];
  const int* pos = (const int*)d_in[1];
  const float* Wq = (const float*)d_in[2];
  const float* Wk = (const float*)d_in[3];
  const float* Wv = (const float*)d_in[4];
  const float* Wo = (const float*)d_in[5];
  const float* qw = (const float*)d_in[6];
  const float* kw = (const float*)d_in[7];
  float* out = (float*)d_out;

  char* p = (char*)d_ws;
  auto take = [&](size_t n) {
    void* r = (void*)p;
    p += (n + 255) & ~(size_t)255;
    return r;
  };
  f16* Xb = (f16*)take((size_t)4096 * 2048 * 2);
  f16* WqkvT = (f16*)take((size_t)3072 * 2048 * 2);
  f16* WoT = (f16*)take((size_t)2048 * 2048 * 2);
  f16* QKVb = (f16*)take((size_t)4096 * 3072 * 2);
  f16* Qr = (f16*)take((size_t)BB * HQ * TT * HD * 2);
  f16* Kr = (f16*)take((size_t)BB * HKV * TT * HD * 2);
  f16* Vt = (f16*)take((size_t)BB * HKV * TT * HD * 2);
  f16* Attn = (f16*)take((size_t)4096 * 2048 * 2);

  k_prep<<<14336, 256, 0, stream>>>(hidden, Wq, Wk, Wv, Wo, Xb, WqkvT, WoT);
  k_gemm8<192, 3072, true><<<256, 512, 0, stream>>>(Xb, WqkvT, QKVb, 4096, 2048);
  k_post<<<6144, 256, 0, stream>>>(QKVb, pos, qw, kw, Qr, Kr, Vt);
  k_attn2<<<dim3(16, 16, 2), 256, 0, stream>>>(Qr, Kr, Vt, Attn);
  k_gemm8<128, 2048, false><<<256, 512, 0, stream>>>(Attn, WoT, out, 4096, 2048);
}